// Round 7
// baseline (263.310 us; speedup 1.0000x reference)
//
#include <hip/hip_runtime.h>

// Occlusion: out = (1/NUM_GRAPHS) * sum_e exp(-||pos[dst_e] - pos[src_e]||)
// batch_idx irrelevant (all segment ids in range; mean over segments ==
// total_sum / NUM_GRAPHS).
//
// ROUND 7 = resubmit of the 3-arm discriminating experiment (rounds 5 & 6
// died to container-infra failures — never ran).
// Divergent-gather wall: R1=R3=R4=80us regardless of MLP/occupancy/lane-count.
//   V0: baseline (nt index loads, normal gathers)      -> reference ~80us
//   V1: V0 + nontemporal GATHERS (no L1 allocation)    -> tests L1-miss-mgmt wall
//   V2: V0 with idx&2047 (L1-resident 16KB, divergent) -> tests TA-walk wall
// Output is taken from V0's partials; V1/V2 write separate scratch.

#define N_EDGES_C   8388608
#define GRID1       2048
#define BLOCK1      256
#define TOTAL_THR   (GRID1 * BLOCK1)          // 524288
#define N_GROUPS    (N_EDGES_C / 4)           // 2097152
#define GPT         (N_GROUPS / TOTAL_THR)    // exactly 4
#define INV_NUM_GRAPHS (1.0f / 1024.0f)

typedef int   v4i __attribute__((ext_vector_type(4)));
typedef float v2f __attribute__((ext_vector_type(2)));

template <int VARIANT>
__global__ __launch_bounds__(BLOCK1) void occl_part(
    const v2f* __restrict__ pos,      // [N_NODES]
    const v4i* __restrict__ src4,     // [E/4]
    const v4i* __restrict__ dst4,     // [E/4]
    float*     __restrict__ partials) // [GRID1]
{
    const int tid = blockIdx.x * BLOCK1 + threadIdx.x;

    // hoist index loads (streaming, nontemporal)
    v4i s[GPT], d[GPT];
    #pragma unroll
    for (int j = 0; j < GPT; ++j) {
        s[j] = __builtin_nontemporal_load(&src4[tid + j * TOTAL_THR]);
        d[j] = __builtin_nontemporal_load(&dst4[tid + j * TOTAL_THR]);
    }

    // hoist all 32 gathers
    v2f ps[16], pd[16];
    #pragma unroll
    for (int j = 0; j < GPT; ++j) {
        #pragma unroll
        for (int k = 0; k < 4; ++k) {
            int is = s[j][k];
            int id = d[j][k];
            if (VARIANT == 2) { is &= 2047; id &= 2047; }  // L1-resident control
            if (VARIANT == 1) {
                ps[j * 4 + k] = __builtin_nontemporal_load(&pos[is]);
                pd[j * 4 + k] = __builtin_nontemporal_load(&pos[id]);
            } else {
                ps[j * 4 + k] = pos[is];
                pd[j * 4 + k] = pos[id];
            }
        }
    }

    // arithmetic: 4 independent accumulator chains
    float acc0 = 0.f, acc1 = 0.f, acc2 = 0.f, acc3 = 0.f;
    #pragma unroll
    for (int k = 0; k < 4; ++k) {
        float dx, dy;
        dx = pd[k +  0][0] - ps[k +  0][0];  dy = pd[k +  0][1] - ps[k +  0][1];
        acc0 += __expf(-sqrtf(dx * dx + dy * dy));
        dx = pd[k +  4][0] - ps[k +  4][0];  dy = pd[k +  4][1] - ps[k +  4][1];
        acc1 += __expf(-sqrtf(dx * dx + dy * dy));
        dx = pd[k +  8][0] - ps[k +  8][0];  dy = pd[k +  8][1] - ps[k +  8][1];
        acc2 += __expf(-sqrtf(dx * dx + dy * dy));
        dx = pd[k + 12][0] - ps[k + 12][0];  dy = pd[k + 12][1] - ps[k + 12][1];
        acc3 += __expf(-sqrtf(dx * dx + dy * dy));
    }
    float acc = (acc0 + acc1) + (acc2 + acc3);

    // wave-64 butterfly reduce
    #pragma unroll
    for (int off = 32; off > 0; off >>= 1)
        acc += __shfl_down(acc, off, 64);

    __shared__ float wave_sums[BLOCK1 / 64];
    const int lane = threadIdx.x & 63;
    const int wid  = threadIdx.x >> 6;
    if (lane == 0) wave_sums[wid] = acc;
    __syncthreads();

    if (threadIdx.x == 0)
        partials[blockIdx.x] = (wave_sums[0] + wave_sums[1]) +
                               (wave_sums[2] + wave_sums[3]);
}

__global__ __launch_bounds__(256) void occlusion_final(
    const float* __restrict__ partials,  // [GRID1] (V0's)
    float*       __restrict__ out)       // [1]
{
    float a = 0.f;
    #pragma unroll
    for (int i = 0; i < GRID1 / 256; ++i)
        a += partials[threadIdx.x + i * 256];

    #pragma unroll
    for (int off = 32; off > 0; off >>= 1)
        a += __shfl_down(a, off, 64);

    __shared__ float w[4];
    if ((threadIdx.x & 63) == 0) w[threadIdx.x >> 6] = a;
    __syncthreads();
    if (threadIdx.x == 0)
        out[0] = ((w[0] + w[1]) + (w[2] + w[3])) * INV_NUM_GRAPHS;
}

extern "C" void kernel_launch(void* const* d_in, const int* in_sizes, int n_in,
                              void* d_out, int out_size, void* d_ws, size_t ws_size,
                              hipStream_t stream) {
    const float* node_pos = (const float*)d_in[0];   // [N_NODES, 2] f32
    const int*   edge_idx = (const int*)d_in[1];     // [2, E] int32
    // d_in[2] = batch_idx — unused (mathematically irrelevant)

    const int E = in_sizes[1] / 2;                   // 8388608
    const int* src = edge_idx;
    const int* dst = edge_idx + E;

    float* p0 = (float*)d_ws;                        // V0 partials  [2048]
    float* p1 = p0 + GRID1;                          // V1 partials  [2048]
    float* p2 = p1 + GRID1;                          // V2 partials  [2048]
    float* out = (float*)d_out;

    const v2f* pos  = reinterpret_cast<const v2f*>(node_pos);
    const v4i* s4   = reinterpret_cast<const v4i*>(src);
    const v4i* dd4  = reinterpret_cast<const v4i*>(dst);

    occl_part<0><<<GRID1, BLOCK1, 0, stream>>>(pos, s4, dd4, p0);
    occl_part<1><<<GRID1, BLOCK1, 0, stream>>>(pos, s4, dd4, p1);
    occl_part<2><<<GRID1, BLOCK1, 0, stream>>>(pos, s4, dd4, p2);
    occlusion_final<<<1, 256, 0, stream>>>(p0, out);
}

// Round 8
// 226.750 us; speedup vs baseline: 1.1612x; 1.1612x over previous
//
#include <hip/hip_runtime.h>

// Occlusion: out = (1/NUM_GRAPHS) * sum_e exp(-||pos[dst_e] - pos[src_e]||)
// batch_idx irrelevant (all segment ids in range; mean over segments ==
// total_sum / NUM_GRAPHS).
//
// ROUND 8 discriminator, name-distinguishable arms (R7's template variants
// all printed as "occl_part"; only slowest arm V1 was visible in top-5):
//   occl_base : correct kernel, ~80us ref; feeds final -> d_out
//   occl_l1res: idx&2047 => 16KB L1-resident table, SAME divergence and
//               SAME 262K gather-instr count. Decides residence-dependence.
//   occl_half : half the groups => 131K gather instrs. Tests linearity.
// Known from R7: nt-gathers HURT (101us, +21MB HBM) — cache allocation is
// good; models remaining: per-instr TA wall (residence-indep) vs L1-service.

#define N_EDGES_C   8388608
#define GRID1       2048
#define BLOCK1      256
#define TOTAL_THR   (GRID1 * BLOCK1)          // 524288
#define N_GROUPS    (N_EDGES_C / 4)           // 2097152
#define GPT         (N_GROUPS / TOTAL_THR)    // exactly 4
#define INV_NUM_GRAPHS (1.0f / 1024.0f)

typedef int   v4i __attribute__((ext_vector_type(4)));
typedef float v2f __attribute__((ext_vector_type(2)));

template <int MASK, int GPTN>
__device__ __forceinline__ float edge_accum(const v2f* __restrict__ pos,
                                            const v4i* __restrict__ src4,
                                            const v4i* __restrict__ dst4)
{
    const int tid = blockIdx.x * BLOCK1 + threadIdx.x;

    v4i s[GPTN], d[GPTN];
    #pragma unroll
    for (int j = 0; j < GPTN; ++j) {
        s[j] = __builtin_nontemporal_load(&src4[tid + j * TOTAL_THR]);
        d[j] = __builtin_nontemporal_load(&dst4[tid + j * TOTAL_THR]);
    }

    v2f ps[4 * GPTN], pd[4 * GPTN];
    #pragma unroll
    for (int j = 0; j < GPTN; ++j) {
        #pragma unroll
        for (int k = 0; k < 4; ++k) {
            int is = s[j][k] & MASK;
            int id = d[j][k] & MASK;
            ps[j * 4 + k] = pos[is];
            pd[j * 4 + k] = pos[id];
        }
    }

    float acc0 = 0.f, acc1 = 0.f, acc2 = 0.f, acc3 = 0.f;
    #pragma unroll
    for (int k = 0; k < GPTN; ++k) {
        float dx, dy;
        dx = pd[4*k+0][0] - ps[4*k+0][0];  dy = pd[4*k+0][1] - ps[4*k+0][1];
        acc0 += __expf(-sqrtf(dx * dx + dy * dy));
        dx = pd[4*k+1][0] - ps[4*k+1][0];  dy = pd[4*k+1][1] - ps[4*k+1][1];
        acc1 += __expf(-sqrtf(dx * dx + dy * dy));
        dx = pd[4*k+2][0] - ps[4*k+2][0];  dy = pd[4*k+2][1] - ps[4*k+2][1];
        acc2 += __expf(-sqrtf(dx * dx + dy * dy));
        dx = pd[4*k+3][0] - ps[4*k+3][0];  dy = pd[4*k+3][1] - ps[4*k+3][1];
        acc3 += __expf(-sqrtf(dx * dx + dy * dy));
    }
    return (acc0 + acc1) + (acc2 + acc3);
}

__device__ __forceinline__ void block_reduce_store(float acc,
                                                   float* __restrict__ partials)
{
    #pragma unroll
    for (int off = 32; off > 0; off >>= 1)
        acc += __shfl_down(acc, off, 64);

    __shared__ float wave_sums[BLOCK1 / 64];
    const int lane = threadIdx.x & 63;
    const int wid  = threadIdx.x >> 6;
    if (lane == 0) wave_sums[wid] = acc;
    __syncthreads();

    if (threadIdx.x == 0)
        partials[blockIdx.x] = (wave_sums[0] + wave_sums[1]) +
                               (wave_sums[2] + wave_sums[3]);
}

__global__ __launch_bounds__(BLOCK1) void occl_base(
    const v2f* __restrict__ pos, const v4i* __restrict__ src4,
    const v4i* __restrict__ dst4, float* __restrict__ partials)
{
    block_reduce_store(edge_accum<-1, GPT>(pos, src4, dst4), partials);
}

__global__ __launch_bounds__(BLOCK1) void occl_l1res(
    const v2f* __restrict__ pos, const v4i* __restrict__ src4,
    const v4i* __restrict__ dst4, float* __restrict__ partials)
{
    block_reduce_store(edge_accum<2047, GPT>(pos, src4, dst4), partials);
}

__global__ __launch_bounds__(BLOCK1) void occl_half(
    const v2f* __restrict__ pos, const v4i* __restrict__ src4,
    const v4i* __restrict__ dst4, float* __restrict__ partials)
{
    block_reduce_store(edge_accum<-1, GPT / 2>(pos, src4, dst4), partials);
}

__global__ __launch_bounds__(256) void occlusion_final(
    const float* __restrict__ partials,  // [GRID1] (occl_base's)
    float*       __restrict__ out)       // [1]
{
    float a = 0.f;
    #pragma unroll
    for (int i = 0; i < GRID1 / 256; ++i)
        a += partials[threadIdx.x + i * 256];

    #pragma unroll
    for (int off = 32; off > 0; off >>= 1)
        a += __shfl_down(a, off, 64);

    __shared__ float w[4];
    if ((threadIdx.x & 63) == 0) w[threadIdx.x >> 6] = a;
    __syncthreads();
    if (threadIdx.x == 0)
        out[0] = ((w[0] + w[1]) + (w[2] + w[3])) * INV_NUM_GRAPHS;
}

extern "C" void kernel_launch(void* const* d_in, const int* in_sizes, int n_in,
                              void* d_out, int out_size, void* d_ws, size_t ws_size,
                              hipStream_t stream) {
    const float* node_pos = (const float*)d_in[0];   // [N_NODES, 2] f32
    const int*   edge_idx = (const int*)d_in[1];     // [2, E] int32
    // d_in[2] = batch_idx — unused (mathematically irrelevant)

    const int E = in_sizes[1] / 2;                   // 8388608
    const int* src = edge_idx;
    const int* dst = edge_idx + E;

    float* p0 = (float*)d_ws;                        // occl_base  partials [2048]
    float* p1 = p0 + GRID1;                          // occl_l1res partials [2048]
    float* p2 = p1 + GRID1;                          // occl_half  partials [2048]
    float* out = (float*)d_out;

    const v2f* pos = reinterpret_cast<const v2f*>(node_pos);
    const v4i* s4  = reinterpret_cast<const v4i*>(src);
    const v4i* d4  = reinterpret_cast<const v4i*>(dst);

    occl_base <<<GRID1, BLOCK1, 0, stream>>>(pos, s4, d4, p0);
    occl_l1res<<<GRID1, BLOCK1, 0, stream>>>(pos, s4, d4, p1);
    occl_half <<<GRID1, BLOCK1, 0, stream>>>(pos, s4, d4, p2);
    occlusion_final<<<1, 256, 0, stream>>>(p0, out);
}